// Round 1
// baseline (234.576 us; speedup 1.0000x reference)
//
#include <hip/hip_runtime.h>

// out = softmax(q @ keys^T) @ keys, fused flash-style.
// q: query [8,256,64,64] NCHW -> rows n=(b,h,w), d=c. keys [2048,256].
// Block = 64 q-rows (one (b,h)), 4 waves x 16 rows. KV tile = 32 keys.
// Score in fp16 hi/lo split (3 MFMAs) for precision; PV in fp16.

typedef _Float16 f16;
typedef f16 f16x8 __attribute__((ext_vector_type(8)));
typedef f16 f16x4 __attribute__((ext_vector_type(4)));
typedef float f32x4 __attribute__((ext_vector_type(4)));

#define D_DIM 256
#define M_KEYS 2048
#define QBLK 64
#define KVB 32
#define NTILES (M_KEYS / KVB)  // 64
#define KPAD 264               // f16 per Kh/Kl row: 528B = 33 16B-slots (odd -> bank spread)
#define VPAD 40                // f16 per VT row: 80B

__global__ __launch_bounds__(256, 2)
void mtr_kernel(const float* __restrict__ keys,
                const float* __restrict__ query,
                float* __restrict__ out) {
  __shared__ f16 Kh[KVB * KPAD];   // 16896 B
  __shared__ f16 Kl[KVB * KPAD];   // 16896 B
  __shared__ f16 VT[D_DIM * VPAD]; // 20480 B  (total 54272 B -> 2 blocks/CU)

  const int tid  = threadIdx.x;
  const int lane = tid & 63;
  const int wave = tid >> 6;   // 0..3
  const int g    = lane >> 4;  // 0..3
  const int qr   = lane & 15;  // q-row within wave's 16 (MFMA col)

  const int nbase  = blockIdx.x * QBLK;  // 512 blocks
  const int b      = nbase >> 12;
  const int hwbase = nbase & 4095;       // h*64

  // ---- q fragments, hi/lo fp16 split. B-operand layout for S^T = mfma(K, q):
  // B[k=d][col=q]: lane holds q[row=qr][d = dt*32 + g*8 + j]
  f16x8 qh[8], ql[8];
  {
    const float* qb = query + ((size_t)b << 20) + hwbase + wave * 16 + qr;
    #pragma unroll
    for (int dt = 0; dt < 8; ++dt) {
      #pragma unroll
      for (int j = 0; j < 8; ++j) {
        int c = dt * 32 + g * 8 + j;
        float v = qb[(size_t)c << 12];   // stride H*W between channels
        f16 h = (f16)v;
        qh[dt][j] = h;
        ql[dt][j] = (f16)(v - (float)h);
      }
    }
  }

  // O[dtile]: O[q = g*4+i][d = dtile*16 + qr] (16x16x16 D-layout)
  f32x4 O[16];
  #pragma unroll
  for (int i = 0; i < 16; ++i) O[i] = (f32x4){0.f, 0.f, 0.f, 0.f};
  float m_run = -INFINITY, l_run = 0.f;

  const int s_key = tid & 31;          // staging: key within tile
  const int s_d0  = (tid >> 5) * 32;   // staging: d-chunk

  for (int t = 0; t < NTILES; ++t) {
    __syncthreads();
    // ---- stage 32-key tile: fp32 -> fp16 hi/lo rows + transposed hi copy ----
    {
      const float* kb = keys + (size_t)(t * KVB + s_key) * D_DIM + s_d0;
      f16 hbuf[32];
      #pragma unroll
      for (int c = 0; c < 4; ++c) {   // 4 chunks of 8 elems
        float4 v0 = *(const float4*)(kb + c * 8);
        float4 v1 = *(const float4*)(kb + c * 8 + 4);
        float vv[8] = {v0.x, v0.y, v0.z, v0.w, v1.x, v1.y, v1.z, v1.w};
        f16x8 hh, ll;
        #pragma unroll
        for (int e = 0; e < 8; ++e) {
          f16 h = (f16)vv[e];
          hh[e] = h;
          ll[e] = (f16)(vv[e] - (float)h);
          hbuf[c * 8 + e] = h;
        }
        *(f16x8*)&Kh[s_key * KPAD + s_d0 + c * 8] = hh;
        *(f16x8*)&Kl[s_key * KPAD + s_d0 + c * 8] = ll;
      }
      #pragma unroll
      for (int e = 0; e < 32; ++e)
        VT[(s_d0 + e) * VPAD + s_key] = hbuf[e];  // VT[d][key]
    }
    __syncthreads();

    // ---- score: S^T[key][q], A = K rows (lane reads 16B of key row kt*16+qr) ----
    f32x4 st[2];
    st[0] = (f32x4){0.f, 0.f, 0.f, 0.f};
    st[1] = (f32x4){0.f, 0.f, 0.f, 0.f};
    #pragma unroll
    for (int dt = 0; dt < 8; ++dt) {
      #pragma unroll
      for (int kt = 0; kt < 2; ++kt) {
        f16x8 ah = *(const f16x8*)&Kh[(kt * 16 + qr) * KPAD + dt * 32 + g * 8];
        f16x8 al = *(const f16x8*)&Kl[(kt * 16 + qr) * KPAD + dt * 32 + g * 8];
        st[kt] = __builtin_amdgcn_mfma_f32_16x16x32_f16(ah, qh[dt], st[kt], 0, 0, 0);
        st[kt] = __builtin_amdgcn_mfma_f32_16x16x32_f16(ah, ql[dt], st[kt], 0, 0, 0);
        st[kt] = __builtin_amdgcn_mfma_f32_16x16x32_f16(al, qh[dt], st[kt], 0, 0, 0);
      }
    }
    // lane holds S[q=qr][key = t*32 + kt*16 + g*4 + i]

    // ---- online softmax over keys (row = qr) ----
    float tmax = -INFINITY;
    #pragma unroll
    for (int kt = 0; kt < 2; ++kt)
      #pragma unroll
      for (int i = 0; i < 4; ++i) tmax = fmaxf(tmax, st[kt][i]);
    tmax = fmaxf(tmax, __shfl_xor(tmax, 16));
    tmax = fmaxf(tmax, __shfl_xor(tmax, 32));

    if (__any(tmax > m_run + 8.f)) {   // defer-max (T13), wave-uniform branch
      float m_new = fmaxf(m_run, tmax);
      float sc = __expf(m_run - m_new);  // exp(-inf)=0 on first tile
      l_run *= sc;
      m_run = m_new;
      float osc0 = __shfl(sc, g * 4 + 0);
      float osc1 = __shfl(sc, g * 4 + 1);
      float osc2 = __shfl(sc, g * 4 + 2);
      float osc3 = __shfl(sc, g * 4 + 3);
      #pragma unroll
      for (int dtile = 0; dtile < 16; ++dtile) {
        O[dtile][0] *= osc0; O[dtile][1] *= osc1;
        O[dtile][2] *= osc2; O[dtile][3] *= osc3;
      }
    }

    float ts = 0.f;
    f16x4 pa[2];
    #pragma unroll
    for (int kt = 0; kt < 2; ++kt)
      #pragma unroll
      for (int i = 0; i < 4; ++i) {
        float e = __expf(st[kt][i] - m_run);  // bounded by e^8
        ts += e;
        pa[kt][i] = (f16)e;
      }
    ts += __shfl_xor(ts, 16);
    ts += __shfl_xor(ts, 32);
    l_run += ts;

    // ---- PV: O[q][d] += P @ K_tile. S^T C-layout == 16x16x16 A-layout: no shuffles.
    #pragma unroll
    for (int kt = 0; kt < 2; ++kt) {
      #pragma unroll
      for (int dtile = 0; dtile < 16; ++dtile) {
        f16x4 vb = *(const f16x4*)&VT[(dtile * 16 + qr) * VPAD + kt * 16 + g * 4];
        O[dtile] = __builtin_amdgcn_mfma_f32_16x16x16f16(pa[kt], vb, O[dtile], 0, 0, 0);
      }
    }
  }

  // ---- epilogue: normalize by row-sum, store NCHW (float4 over w) ----
  float r0 = 1.f / __shfl(l_run, g * 4 + 0);
  float r1 = 1.f / __shfl(l_run, g * 4 + 1);
  float r2 = 1.f / __shfl(l_run, g * 4 + 2);
  float r3 = 1.f / __shfl(l_run, g * 4 + 3);
  float* ob = out + ((size_t)b << 20) + hwbase + wave * 16 + g * 4;
  #pragma unroll
  for (int dtile = 0; dtile < 16; ++dtile) {
    int c = dtile * 16 + qr;
    float4 w4;
    w4.x = O[dtile][0] * r0;
    w4.y = O[dtile][1] * r1;
    w4.z = O[dtile][2] * r2;
    w4.w = O[dtile][3] * r3;
    *(float4*)(ob + ((size_t)c << 12)) = w4;
  }
}

extern "C" void kernel_launch(void* const* d_in, const int* in_sizes, int n_in,
                              void* d_out, int out_size, void* d_ws, size_t ws_size,
                              hipStream_t stream) {
  const float* keys  = (const float*)d_in[0];
  const float* query = (const float*)d_in[1];
  float* out = (float*)d_out;
  hipLaunchKernelGGL(mtr_kernel, dim3(512), dim3(256), 0, stream, keys, query, out);
}